// Round 4
// baseline (316.191 us; speedup 1.0000x reference)
//
#include <hip/hip_runtime.h>
#include <math.h>

#define O_  32
#define I_  32
#define K_  13
#define N_  4096
#define IK  (I_ * K_)     // 416
#define OIK (O_ * IK)     // 13312
#define NB  4             // n's per block
#define REP 5             // DIAGNOSTIC: stream the mask 5x so the kernel
                          // dispatch outranks the 127us harness fills and
                          // finally shows its own rocprof counters.

typedef float f32x4 __attribute__((ext_vector_type(4)));

// Round 4 (instrumented): exact R1 structure (best known, 291.5us), but the
// streaming phase repeats REP times inside the kernel. Gather runs once;
// each rep recomputes and rewrites identical output (idempotent, passes
// correctness). Per-rep marginal time isolates the pure mask-stream phase;
// FETCH_SIZE across reps measures L3 retention of the 208 MiB mask.
__global__ __launch_bounds__(256, 4) void plaq_kernel(
    const float* __restrict__ x,      // (I, N)
    const float* __restrict__ W,      // (O, I, K)
    const float* __restrict__ b,      // (O,)
    const float* __restrict__ mask,   // (N, O, I, K)
    const int*   __restrict__ shifts, // (N, K)
    float* __restrict__ out)          // (O, N)
{
    __shared__ __align__(16) float g_lds[NB][IK];
    const int n0  = blockIdx.x * NB;
    const int tid = threadIdx.x;

    // Gather g[nl][i*13+k] = x[i*N + shifts[(n0+nl)*13+k]]  (1664 elems).
    for (int idx = tid; idx < NB * IK; idx += 256) {
        int nl = idx / IK;
        int r  = idx - nl * IK;
        int i  = r / K_;
        int k  = r - i * K_;
        int s  = shifts[(n0 + nl) * K_ + k];
        g_lds[nl][r] = x[i * N_ + s];
    }

    // Hoist W into registers while the gather is in flight (independent).
    const int o  = tid >> 3;
    const int s8 = tid & 7;
    const f32x4* w4 = (const f32x4*)(W + o * IK);
    f32x4 w[13];
#pragma unroll
    for (int m = 0; m < 13; ++m) w[m] = w4[s8 + 8 * m];
    const float bo = b[o];

    __syncthreads();

    const float scale = (float)((2.0 + 2.0 * M_E) / (M_E - 1.0));

#pragma unroll 1
    for (int rep = 0; rep < REP; ++rep) {
        for (int nl = 0; nl < NB; ++nl) {
            const int n = n0 + nl;
            const f32x4* m4 = (const f32x4*)(mask + (size_t)n * OIK + o * IK);
            const f32x4* g4 = (const f32x4*)(&g_lds[nl][0]);

            float a0 = 0.f, a1 = 0.f, a2 = 0.f, a3 = 0.f;
#pragma unroll
            for (int m = 0; m < 13; ++m) {
                f32x4 mv = m4[s8 + 8 * m];      // plain load: allow L3
                f32x4 wg = w[m] * g4[s8 + 8 * m];
                a0 = fmaf(mv.x, wg.x, a0);
                a1 = fmaf(mv.y, wg.y, a1);
                a2 = fmaf(mv.z, wg.z, a2);
                a3 = fmaf(mv.w, wg.w, a3);
            }
            float acc = (a0 + a1) + (a2 + a3);

            // Reduce across the 8 lanes sharing this o (within one wave).
            acc += __shfl_down(acc, 4);
            acc += __shfl_down(acc, 2);
            acc += __shfl_down(acc, 1);

            if (s8 == 0) {
                float y  = acc + bo;
                float sg = 1.0f / (1.0f + __expf(-y));
                out[o * N_ + n] = (sg - 0.5f) * scale;
            }
        }
    }
}

extern "C" void kernel_launch(void* const* d_in, const int* in_sizes, int n_in,
                              void* d_out, int out_size, void* d_ws, size_t ws_size,
                              hipStream_t stream) {
    const float* x      = (const float*)d_in[0];
    const float* Wconv  = (const float*)d_in[1];
    const float* bconv  = (const float*)d_in[2];
    const float* mask   = (const float*)d_in[3];
    const int*   shifts = (const int*)d_in[4];
    float* out = (float*)d_out;

    plaq_kernel<<<N_ / NB, 256, 0, stream>>>(x, Wconv, bconv, mask, shifts, out);
}

// Round 5
// 307.032 us; speedup vs baseline: 1.0298x; 1.0298x over previous
//
#include <hip/hip_runtime.h>
#include <math.h>

#define O_  32
#define I_  32
#define K_  13
#define N_  4096
#define IK  (I_ * K_)     // 416
#define OIK (O_ * IK)     // 13312
#define NB  4             // n's per block
#define GTOT (NB * IK)    // 1664 gathered elems per block
#define PF  7             // mask m-slots prefetched for nl=0 (28 VGPRs)

typedef float f32x4 __attribute__((ext_vector_type(4)));

typedef const float __attribute__((address_space(1)))* gas_ptr;
typedef float __attribute__((address_space(3)))* las_ptr;

// Round 5: measured model = 240us harness floor + ~18.5us gather+launch +
// 33us cold HBM mask stream (roofline). Attack the 18.5:
//  - gather via global_load_lds: dest g_lds[tid+256*it] is exactly the
//    wave-uniform-base + lane*4 layout the instruction writes; kills the
//    load->VGPR->ds_write round trip and its latency level.
//  - shift loads all issued independently first (one latency level).
//  - PF=7 of 13 nl=0 mask slots prefetched at cycle 0 so the HBM stream
//    rolls during the gather. VGPR ~115 < 128 -> still 4 waves/SIMD,
//    all 1024 blocks resident in one pass (R3's regression was the 3-wave cut).
__global__ __launch_bounds__(256, 4) void plaq_kernel(
    const float* __restrict__ x,      // (I, N)
    const float* __restrict__ W,      // (O, I, K)
    const float* __restrict__ b,      // (O,)
    const float* __restrict__ mask,   // (N, O, I, K)
    const int*   __restrict__ shifts, // (N, K)
    float* __restrict__ out)          // (O, N)
{
    __shared__ __align__(16) float g_lds[GTOT];
    const int n0  = blockIdx.x * NB;
    const int tid = threadIdx.x;
    const int o   = tid >> 3;
    const int s8  = tid & 7;

    // ---- Phase 0: start the nl=0 mask stream immediately (off critical path).
    const f32x4* m4_0 = (const f32x4*)(mask + (size_t)n0 * OIK + o * IK);
    f32x4 mv0[PF];
#pragma unroll
    for (int m = 0; m < PF; ++m) mv0[m] = m4_0[s8 + 8 * m];

    // ---- Phase 1: all shift loads issued independently (one latency level).
    int sv[7];
#pragma unroll
    for (int it = 0; it < 7; ++it) {
        int idx = tid + 256 * it;
        if (idx >= GTOT) idx = GTOT - 1;   // only pads waves that skip phase 2
        int nl  = idx / IK;
        int r   = idx - nl * IK;
        int k   = r - (r / K_) * K_;
        sv[it]  = shifts[(n0 + nl) * K_ + k];
    }

    // ---- Phase 2: direct global->LDS gather. For iteration it, this wave's
    // lanes write g_lds[256*it + wbase + lane] = base + lane*4 (linear). ----
    {
        const int wbase = tid & ~63;       // wave-uniform offset within block
#pragma unroll
        for (int it = 0; it < 7; ++it) {
            if (256 * it + wbase < GTOT) { // wave-uniform predicate (it==6: waves 0,1 only)
                int idx = tid + 256 * it;
                int nl  = idx / IK;
                int r   = idx - nl * IK;
                int i   = r / K_;
                const float* src = x + (size_t)i * N_ + sv[it];
                __builtin_amdgcn_global_load_lds((gas_ptr)src,
                                                 (las_ptr)&g_lds[256 * it + wbase],
                                                 4, 0, 0);
            }
        }
    }

    // W into registers (independent; in flight until the barrier drain).
    const f32x4* w4 = (const f32x4*)(W + o * IK);
    f32x4 w[13];
#pragma unroll
    for (int m = 0; m < 13; ++m) w[m] = w4[s8 + 8 * m];
    const float bo = b[o];

    __syncthreads();

    const float scale = (float)((2.0 + 2.0 * M_E) / (M_E - 1.0));

    for (int nl = 0; nl < NB; ++nl) {
        const int n = n0 + nl;
        const f32x4* m4 = (const f32x4*)(mask + (size_t)n * OIK + o * IK);
        const f32x4* g4 = (const f32x4*)(&g_lds[nl * IK]);

        float a0 = 0.f, a1 = 0.f, a2 = 0.f, a3 = 0.f;
#pragma unroll
        for (int m = 0; m < 13; ++m) {
            f32x4 mv = (nl == 0 && m < PF) ? mv0[m] : m4[s8 + 8 * m];
            f32x4 wg = w[m] * g4[s8 + 8 * m];
            a0 = fmaf(mv.x, wg.x, a0);
            a1 = fmaf(mv.y, wg.y, a1);
            a2 = fmaf(mv.z, wg.z, a2);
            a3 = fmaf(mv.w, wg.w, a3);
        }
        float acc = (a0 + a1) + (a2 + a3);

        // Reduce across the 8 lanes sharing this o (within one wave).
        acc += __shfl_down(acc, 4);
        acc += __shfl_down(acc, 2);
        acc += __shfl_down(acc, 1);

        if (s8 == 0) {
            float y  = acc + bo;
            float sg = 1.0f / (1.0f + __expf(-y));
            out[o * N_ + n] = (sg - 0.5f) * scale;
        }
    }
}

extern "C" void kernel_launch(void* const* d_in, const int* in_sizes, int n_in,
                              void* d_out, int out_size, void* d_ws, size_t ws_size,
                              hipStream_t stream) {
    const float* x      = (const float*)d_in[0];
    const float* Wconv  = (const float*)d_in[1];
    const float* bconv  = (const float*)d_in[2];
    const float* mask   = (const float*)d_in[3];
    const int*   shifts = (const int*)d_in[4];
    float* out = (float*)d_out;

    plaq_kernel<<<N_ / NB, 256, 0, stream>>>(x, Wconv, bconv, mask, shifts, out);
}